// Round 6
// baseline (270.679 us; speedup 1.0000x reference)
//
#include <hip/hip_runtime.h>
#include <cstdint>
#include <cstddef>

// Problem constants
#define CIN_K  512
#define WW_    38
#define BHW    1444          // 38*38
#define NOUT   255
#define MTOT   46208         // 32*1444 == 722*64

#define BK      64
#define NCHUNK  (CIN_K / BK)     // 8
#define ROWDW   65               // dword stride per k-row in As (64 m + 1 pad)
#define CHUNKDW (BK * ROWDW)     // 4160 dw per buffer (16,640 B)
#define EPSTR   260              // epilogue row stride (dw): holds 256 cols, 260%32==4
// EP total = 16 * 260 = 4160 dw — exactly aliases buffer 0.

typedef __attribute__((ext_vector_type(8))) short  bf16x8;
typedef __attribute__((ext_vector_type(4))) float  floatx4;
typedef const __attribute__((address_space(1))) unsigned int* gas_ptr;
typedef __attribute__((address_space(3)))       unsigned int* las_ptr;

static __device__ __forceinline__ unsigned f2bf(float f) {
    unsigned u = __builtin_bit_cast(unsigned, f);
    return (u + 0x7FFFu + ((u >> 16) & 1u)) >> 16;   // RNE to bf16
}

// ---- pass 1: cw fp32 [255][512] -> wb bf16 [256][512], row 255 zeroed ----
__global__ void conv_w_to_bf16(const float* __restrict__ cw,
                               unsigned short* __restrict__ wb) {
    int tg   = blockIdx.x * 256 + threadIdx.x;   // 0..16383
    int base = tg * 8;
    int n    = base >> 9;
    unsigned rr[4] = {0u, 0u, 0u, 0u};
    if (n < NOUT) {
        float4 v0 = *(const float4*)(cw + base);
        float4 v1 = *(const float4*)(cw + base + 4);
        rr[0] = f2bf(v0.x) | (f2bf(v0.y) << 16);
        rr[1] = f2bf(v0.z) | (f2bf(v0.w) << 16);
        rr[2] = f2bf(v1.x) | (f2bf(v1.y) << 16);
        rr[3] = f2bf(v1.z) | (f2bf(v1.w) << 16);
    }
    *(uint4*)(wb + base) = *(uint4*)rr;
}

// ---- pass 2: GEMM with fire-and-forget LDS staging + fused YOLO decode ----
// Block: 64 m x 256 n (full N). Wave w: n-slice [w*64, w*64+64), all 64 m.
// A: fp32 k-major in LDS, double-buffered BK=64, staged via global_load_lds
// (per-lane global gather; LDS dest = wave-uniform base + lane*4).
// B: bf16 direct from L2 (wb is 256 KB).
__global__ __launch_bounds__(256, 3)
void yolo_head(const float* __restrict__ xin,          // [32,512,38,38] fp32
               const unsigned short* __restrict__ wb,  // [256,512] bf16
               const float* __restrict__ cb,           // [255] fp32
               float* __restrict__ out)                // [46208,255] fp32
{
    __shared__ float smem[2 * CHUNKDW];                // 33,280 B

    const int t    = threadIdx.x;
    const int w    = t >> 6;       // wave id -> n-slice w*64; staging k-subchunk
    const int lane = t & 63;
    const int l15  = lane & 15;
    const int q    = lane >> 4;
    const int m0   = blockIdx.x * 64;

    // per-lane A base: lane <-> m row (handles image straddle transparently)
    const int m  = m0 + lane;
    const int bi = m / BHW;
    const int hw = m - bi * BHW;
    const float* pal = xin + (size_t)bi * (CIN_K * BHW) + hw;

    // B frag base: n = w*64 + j*16 + l15, k = q*8 (+ chunk offsets)
    const unsigned short* pbw = wb + (size_t)(w * 64 + l15) * CIN_K + q * 8;

    floatx4 acc[4][4];
#pragma unroll
    for (int i = 0; i < 4; ++i)
#pragma unroll
        for (int j = 0; j < 4; ++j)
            acc[i][j] = (floatx4){0.f, 0.f, 0.f, 0.f};

#define STAGE(buf, k0)                                                        \
    {                                                                         \
        const float* g = pal + (size_t)((k0) + w * 16) * BHW;                 \
        float* lr = smem + (buf) * CHUNKDW + (w * 16) * ROWDW;                \
        _Pragma("unroll")                                                     \
        for (int s_ = 0; s_ < 16; ++s_) {                                     \
            __builtin_amdgcn_global_load_lds((gas_ptr)g, (las_ptr)lr, 4, 0, 0);\
            g  += BHW;                                                        \
            lr += ROWDW;                                                      \
        }                                                                     \
    }

    STAGE(0, 0)                      // prologue: chunk 0 in flight

#pragma unroll
    for (int s = 0; s < NCHUNK; ++s) {
        __syncthreads();             // drains chunk-s loads (issued 1 chunk ago)
        if (s < NCHUNK - 1) STAGE((s + 1) & 1, (s + 1) * BK)   // fire-and-forget

        const float* Ab = smem + (s & 1) * CHUNKDW;
#pragma unroll
        for (int kc = 0; kc < 2; ++kc) {
            bf16x8 bfr[4];
#pragma unroll
            for (int j = 0; j < 4; ++j) {
                uint4 bv = *(const uint4*)(pbw + s * BK + kc * 32 + (size_t)j * 16 * CIN_K);
                bfr[j] = __builtin_bit_cast(bf16x8, bv);
            }
#pragma unroll
            for (int i = 0; i < 4; ++i) {
                const float* ap = Ab + (kc * 32 + q * 8) * ROWDW + i * 16 + l15;
                float v[8];
#pragma unroll
                for (int u = 0; u < 8; ++u) v[u] = ap[u * ROWDW];
                unsigned pk[4];
#pragma unroll
                for (int u2 = 0; u2 < 4; ++u2)
                    pk[u2] = f2bf(v[2 * u2]) | (f2bf(v[2 * u2 + 1]) << 16);
                bf16x8 af = __builtin_bit_cast(bf16x8, *(int4*)pk);
#pragma unroll
                for (int j = 0; j < 4; ++j)
                    acc[i][j] = __builtin_amdgcn_mfma_f32_16x16x32_bf16(
                                    af, bfr[j], acc[i][j], 0, 0, 0);
            }
        }
    }

    // -------- fused YOLO decode (in place on acc) --------------------------
    // C/D layout: col(n) = l15 (+16j), row(m) = i*16 + q*4 + r
#pragma unroll
    for (int j = 0; j < 4; ++j) {
        int   n    = w * 64 + j * 16 + l15;
        int   nc   = n < NOUT ? n : NOUT - 1;
        int   ai   = nc / 85;
        int   ji   = nc - ai * 85;
        float bias = cb[nc];
        float aw   = (ai == 0) ? 30.f : (ai == 1) ? 62.f : 59.f;
        float ah   = (ai == 0) ? 61.f : (ai == 1) ? 45.f : 119.f;
#pragma unroll
        for (int i = 0; i < 4; ++i)
#pragma unroll
            for (int r = 0; r < 4; ++r) {
                int   md  = m0 + i * 16 + q * 4 + r;
                int   rem = md % BHW;
                int   hh  = rem / WW_;
                float v   = acc[i][j][r] + bias;
                float res;
                if (ji == 0)      res = (1.f / (1.f + __expf(-v)) + (float)(rem - hh * WW_)) * 16.f;
                else if (ji == 1) res = (1.f / (1.f + __expf(-v)) + (float)hh) * 16.f;
                else if (ji == 2) res = __expf(v) * aw;
                else if (ji == 3) res = __expf(v) * ah;
                else              res = v;
                acc[i][j][r] = res;
            }
    }

    // -------- epilogue: 4 phases of 16-row LDS transpose -> aligned stores --
    // EP[16][EPSTR] fp32 = 4160 dw, aliases buffer 0.
    float* EP = smem;
#pragma unroll 1
    for (int p = 0; p < 4; ++p) {
        __syncthreads();              // K-loop / previous phase readers done

        // deposit: wave w contributes its n-slice for m-rows p*16 .. p*16+15
#pragma unroll
        for (int j = 0; j < 4; ++j)
#pragma unroll
            for (int r = 0; r < 4; ++r)
                EP[(q * 4 + r) * EPSTR + w * 64 + j * 16 + l15] = acc[p][j][r];

        __syncthreads();              // EP chunk complete

        // store 16 rows * 255 = 4080 floats, contiguous, float4 per lane
        float* ob = out + (size_t)(m0 + p * 16) * NOUT;
#pragma unroll
        for (int s2 = 0; s2 < 4; ++s2) {
            int f4 = s2 * 256 + t;
            if (f4 < 1020) {
                int   f = f4 * 4;
                float vv[4];
#pragma unroll
                for (int e = 0; e < 4; ++e) {
                    int fe = f + e;
                    int mr = fe / NOUT;
                    int x  = fe - mr * NOUT;
                    vv[e]  = EP[mr * EPSTR + x];
                }
                *(float4*)(ob + f) = make_float4(vv[0], vv[1], vv[2], vv[3]);
            }
        }
    }
}

extern "C" void kernel_launch(void* const* d_in, const int* in_sizes, int n_in,
                              void* d_out, int out_size, void* d_ws, size_t ws_size,
                              hipStream_t stream) {
    const float* xin = (const float*)d_in[0];
    const float* cw  = (const float*)d_in[1];
    const float* cb  = (const float*)d_in[2];
    float*       out = (float*)d_out;
    unsigned short* wb = (unsigned short*)d_ws;   // 256*512*2 = 256 KiB

    hipLaunchKernelGGL(conv_w_to_bf16, dim3(64), dim3(256), 0, stream, cw, wb);
    hipLaunchKernelGGL(yolo_head, dim3(MTOT / 64), dim3(256), 0, stream,
                       xin, wb, cb, out);
}